// Round 1
// baseline (394.124 us; speedup 1.0000x reference)
//
#include <hip/hip_runtime.h>
#include <cstdint>
#include <cstddef>

typedef float f32x4 __attribute__((ext_vector_type(4)));

#define FP8_MAX 448.0f
#define BM 128
#define BN 128
#define BK 64

// async global->LDS, 16B per lane; LDS dest is wave-uniform base + lane*16
#define GLOAD16(gp, lp)                                          \
  __builtin_amdgcn_global_load_lds(                              \
      (const __attribute__((address_space(1))) void*)(gp),       \
      (__attribute__((address_space(3))) void*)(lp), 16, 0, 0)

__device__ __forceinline__ uint32_t pack4_e4m3(float a, float b, float c, float d) {
  // v_cvt_pk_fp8_f32: RNE, saturating, OCP e4m3fn on gfx950
  int p = __builtin_amdgcn_cvt_pk_fp8_f32(a, b, 0, false);
  p = __builtin_amdgcn_cvt_pk_fp8_f32(c, d, p, true);
  return (uint32_t)p;
}

// One block (256 threads) per row of K=4096 fp32.
// amax -> scale=448/amax -> q=RNE(clip(x*scale,±448)) -> recip=1/scale
__global__ __launch_bounds__(256) void quant_rowwise(
    const float* __restrict__ X, uint8_t* __restrict__ Q,
    float* __restrict__ recip, int K) {
  const int row = blockIdx.x;
  const int tid = threadIdx.x;
  const float4* __restrict__ x4 = (const float4*)(X + (size_t)row * K);
  float4 v[4];
  float am = 0.0f;
#pragma unroll
  for (int i = 0; i < 4; ++i) {
    v[i] = x4[i * 256 + tid];
    am = fmaxf(am, fmaxf(fmaxf(fabsf(v[i].x), fabsf(v[i].y)),
                         fmaxf(fabsf(v[i].z), fabsf(v[i].w))));
  }
#pragma unroll
  for (int off = 32; off > 0; off >>= 1)
    am = fmaxf(am, __shfl_xor(am, off));
  __shared__ float smax[4];
  const int wave = tid >> 6, lane = tid & 63;
  if (lane == 0) smax[wave] = am;
  __syncthreads();
  am = fmaxf(fmaxf(smax[0], smax[1]), fmaxf(smax[2], smax[3]));
  am = fmaxf(am, 1e-12f);
  const float scale = FP8_MAX / am;          // exact IEEE div (no fast-math)
  if (tid == 0) recip[row] = 1.0f / scale;   // matches reference 1.0/scale
  uint32_t* __restrict__ q32 = (uint32_t*)(Q + (size_t)row * K);
#pragma unroll
  for (int i = 0; i < 4; ++i) {
    float a = fminf(fmaxf(v[i].x * scale, -FP8_MAX), FP8_MAX);
    float b = fminf(fmaxf(v[i].y * scale, -FP8_MAX), FP8_MAX);
    float c = fminf(fmaxf(v[i].z * scale, -FP8_MAX), FP8_MAX);
    float d = fminf(fmaxf(v[i].w * scale, -FP8_MAX), FP8_MAX);
    q32[i * 256 + tid] = pack4_e4m3(a, b, c, d);
  }
}

// C[M,N] = (Aq[M,K] . Bq[N,K]^T) * xs[m] * ws[n] + bias[n]
// 128x128 tile, 4 waves 2x2 (each 64x64 = 4x4 frags of 16x16), BK=64.
// LDS stored layout XOR-swizzled on byte bits 4,5 by (row&3) — applied to
// BOTH the global source address (16B-chunk granular) and the ds_read addr.
__global__ __launch_bounds__(256) void gemm_fp8(
    const uint8_t* __restrict__ Aq, const uint8_t* __restrict__ Bq,
    const float* __restrict__ xs, const float* __restrict__ ws,
    const float* __restrict__ bias, float* __restrict__ C,
    int M, int N, int K) {
  __shared__ uint8_t lA[BM * BK];  // 8 KB
  __shared__ uint8_t lB[BN * BK];  // 8 KB
  const int tid = threadIdx.x;
  const int wave = tid >> 6, lane = tid & 63;
  const int wr = wave >> 1, wc = wave & 1;
  const int row0 = blockIdx.x * BM, col0 = blockIdx.y * BN;

  const int s_r = lane >> 2;        // row within a 16-row segment
  const int s_c = (lane & 3) * 16;  // stored col byte (16B chunk)

  f32x4 acc[4][4];
#pragma unroll
  for (int m = 0; m < 4; ++m)
#pragma unroll
    for (int n = 0; n < 4; ++n) acc[m][n] = {0.f, 0.f, 0.f, 0.f};

  const int fr = lane & 15;        // fragment row/col index
  const int q8 = (lane >> 4) * 8;  // k-offset of this lane's 8 bytes

  const int nk = K / BK;
  for (int kt = 0; kt < nk; ++kt) {
    const int k0 = kt * BK;
#pragma unroll
    for (int p = 0; p < 2; ++p) {
      const int s = wave + p * 4;          // 1KB segment id (wave-uniform)
      const int r = s * 16 + s_r;          // tile row this lane feeds
      const int csw = s_c ^ ((r & 3) << 4);  // pre-swizzled source col
      GLOAD16(Aq + (size_t)(row0 + r) * K + k0 + csw, &lA[s * 1024]);
    }
#pragma unroll
    for (int p = 0; p < 2; ++p) {
      const int s = wave + p * 4;
      const int r = s * 16 + s_r;
      const int csw = s_c ^ ((r & 3) << 4);
      GLOAD16(Bq + (size_t)(col0 + r) * K + k0 + csw, &lB[s * 1024]);
    }
    __syncthreads();  // compiler emits vmcnt(0) drain here
#pragma unroll
    for (int ks = 0; ks < 2; ++ks) {
      long a[4], b[4];
#pragma unroll
      for (int m = 0; m < 4; ++m) {
        const int r = wr * 64 + m * 16 + fr;
        const int col = (ks * 32 + q8) ^ ((r & 3) << 4);
        a[m] = *(const long*)&lA[r * BK + col];
      }
#pragma unroll
      for (int n = 0; n < 4; ++n) {
        const int r = wc * 64 + n * 16 + fr;
        const int col = (ks * 32 + q8) ^ ((r & 3) << 4);
        b[n] = *(const long*)&lB[r * BK + col];
      }
#pragma unroll
      for (int m = 0; m < 4; ++m)
#pragma unroll
        for (int n = 0; n < 4; ++n)
          acc[m][n] = __builtin_amdgcn_mfma_f32_16x16x32_fp8_fp8(
              a[m], b[n], acc[m][n], 0, 0, 0);
    }
    __syncthreads();
  }

  // epilogue: C/D layout col=lane&15, row=(lane>>4)*4+i (dtype-independent)
  const int r4 = (lane >> 4) * 4;
#pragma unroll
  for (int m = 0; m < 4; ++m) {
#pragma unroll
    for (int n = 0; n < 4; ++n) {
      const int c = col0 + wc * 64 + n * 16 + fr;
      const float wsn = ws[c];
      const float bb = bias[c];
#pragma unroll
      for (int i = 0; i < 4; ++i) {
        const int r = row0 + wr * 64 + m * 16 + r4 + i;
        C[(size_t)r * N + c] = acc[m][n][i] * xs[r] * wsn + bb;
      }
    }
  }
}

extern "C" void kernel_launch(void* const* d_in, const int* in_sizes, int n_in,
                              void* d_out, int out_size, void* d_ws, size_t ws_size,
                              hipStream_t stream) {
  const float* input = (const float*)d_in[0];   // [M,K] fp32
  const float* weight = (const float*)d_in[1];  // [N,K] fp32
  const float* bias = (const float*)d_in[2];    // [N]   fp32
  float* out = (float*)d_out;                   // [M,N] fp32

  const int K = 4096;
  const int N = in_sizes[2];
  const int M = in_sizes[0] / K;

  // workspace layout: qA[M*K] | qW[N*K] | xs[M] | ws[N]  (~50.4 MB)
  uint8_t* qA = (uint8_t*)d_ws;
  uint8_t* qW = qA + (size_t)M * K;
  float* xsc = (float*)(qW + (size_t)N * K);
  float* wsc = xsc + M;

  quant_rowwise<<<M, 256, 0, stream>>>(input, qA, xsc, K);
  quant_rowwise<<<N, 256, 0, stream>>>(weight, qW, wsc, K);

  dim3 grid(M / BM, N / BN);
  gemm_fp8<<<grid, 256, 0, stream>>>(qA, qW, xsc, wsc, bias, out, M, N, K);
}

// Round 2
// 283.803 us; speedup vs baseline: 1.3887x; 1.3887x over previous
//
#include <hip/hip_runtime.h>
#include <cstdint>
#include <cstddef>

typedef float f32x4 __attribute__((ext_vector_type(4)));
typedef long long2v __attribute__((ext_vector_type(2)));

#define FP8_MAX 448.0f
#define BM 128
#define BN 128
#define BK 64

// async global->LDS, 16B per lane; LDS dest is wave-uniform base + lane*16
#define GLOAD16(gp, lp)                                          \
  __builtin_amdgcn_global_load_lds(                              \
      (const __attribute__((address_space(1))) void*)(gp),       \
      (__attribute__((address_space(3))) void*)(lp), 16, 0, 0)

__device__ __forceinline__ uint32_t pack4_e4m3(float a, float b, float c, float d) {
  // v_cvt_pk_fp8_f32: RNE, saturating, OCP e4m3fn on gfx950
  int p = __builtin_amdgcn_cvt_pk_fp8_f32(a, b, 0, false);
  p = __builtin_amdgcn_cvt_pk_fp8_f32(c, d, p, true);
  return (uint32_t)p;
}

// One block (256 threads) per row of K=4096 fp32.
// amax -> scale=448/amax -> q=RNE(clip(x*scale,±448)) -> recip=1/scale
__global__ __launch_bounds__(256) void quant_rowwise(
    const float* __restrict__ X, uint8_t* __restrict__ Q,
    float* __restrict__ recip, int K) {
  const int row = blockIdx.x;
  const int tid = threadIdx.x;
  const float4* __restrict__ x4 = (const float4*)(X + (size_t)row * K);
  float4 v[4];
  float am = 0.0f;
#pragma unroll
  for (int i = 0; i < 4; ++i) {
    v[i] = x4[i * 256 + tid];
    am = fmaxf(am, fmaxf(fmaxf(fabsf(v[i].x), fabsf(v[i].y)),
                         fmaxf(fabsf(v[i].z), fabsf(v[i].w))));
  }
#pragma unroll
  for (int off = 32; off > 0; off >>= 1)
    am = fmaxf(am, __shfl_xor(am, off));
  __shared__ float smax[4];
  const int wave = tid >> 6, lane = tid & 63;
  if (lane == 0) smax[wave] = am;
  __syncthreads();
  am = fmaxf(fmaxf(smax[0], smax[1]), fmaxf(smax[2], smax[3]));
  am = fmaxf(am, 1e-12f);
  const float scale = FP8_MAX / am;          // exact IEEE div (no fast-math)
  if (tid == 0) recip[row] = 1.0f / scale;   // matches reference 1.0/scale
  uint32_t* __restrict__ q32 = (uint32_t*)(Q + (size_t)row * K);
#pragma unroll
  for (int i = 0; i < 4; ++i) {
    float a = fminf(fmaxf(v[i].x * scale, -FP8_MAX), FP8_MAX);
    float b = fminf(fmaxf(v[i].y * scale, -FP8_MAX), FP8_MAX);
    float c = fminf(fmaxf(v[i].z * scale, -FP8_MAX), FP8_MAX);
    float d = fminf(fmaxf(v[i].w * scale, -FP8_MAX), FP8_MAX);
    q32[i * 256 + tid] = pack4_e4m3(a, b, c, d);
  }
}

// C[M,N] = (Aq[M,K] . Bq[N,K]^T) * xs[m] * ws[n] + bias[n]
// 128x128 tile, 4 waves 2x2 (each 64x64 = 4x4 frags of 16x16), BK=64.
//
// LDS swizzle (both-sides, rule #21): stored[r][chunk c] = logical[r][c ^ (r&3)]
// (16B chunks). Staging pre-swizzles the GLOBAL source column; reads XOR the
// chunk index. Reads are ds_read_b128: lane group g=lane>>4 reads tile-k chunk
// g; its two 8B halves feed two separate MFMAs (k-permutation is legal since
// A and B use the same tile-k->MFMA-slot assignment and the k-sum commutes).
// Granule occupancy is perfectly uniform (8 lanes x 8B per granule) -> zero
// bank conflict.
__global__ __launch_bounds__(256) void gemm_fp8(
    const uint8_t* __restrict__ Aq, const uint8_t* __restrict__ Bq,
    const float* __restrict__ xs, const float* __restrict__ ws,
    const float* __restrict__ bias, float* __restrict__ C,
    int M, int N, int K) {
  __shared__ uint8_t lA[BM * BK];  // 8 KB
  __shared__ uint8_t lB[BN * BK];  // 8 KB
  const int tid = threadIdx.x;
  const int wave = tid >> 6, lane = tid & 63;
  const int wr = wave >> 1, wc = wave & 1;
  const int row0 = blockIdx.x * BM, col0 = blockIdx.y * BN;

  const int s_r = lane >> 2;        // row within a 16-row segment
  const int s_c = (lane & 3) * 16;  // stored col byte (16B chunk)

  f32x4 acc[4][4];
#pragma unroll
  for (int m = 0; m < 4; ++m)
#pragma unroll
    for (int n = 0; n < 4; ++n) acc[m][n] = {0.f, 0.f, 0.f, 0.f};

  const int fr = lane & 15;   // fragment row/col index
  const int g = lane >> 4;    // lane's tile-k chunk (16B) for this kt

  const int nk = K / BK;
  for (int kt = 0; kt < nk; ++kt) {
    const int k0 = kt * BK;
#pragma unroll
    for (int p = 0; p < 2; ++p) {
      const int s = wave + p * 4;            // 1KB segment id (wave-uniform)
      const int r = s * 16 + s_r;            // tile row this lane feeds
      const int csw = s_c ^ ((r & 3) << 4);  // pre-swizzled source col
      GLOAD16(Aq + (size_t)(row0 + r) * K + k0 + csw, &lA[s * 1024]);
    }
#pragma unroll
    for (int p = 0; p < 2; ++p) {
      const int s = wave + p * 4;
      const int r = s * 16 + s_r;
      const int csw = s_c ^ ((r & 3) << 4);
      GLOAD16(Bq + (size_t)(col0 + r) * K + k0 + csw, &lB[s * 1024]);
    }
    __syncthreads();  // compiler emits vmcnt(0) drain here

    long2v a[4], b[4];
#pragma unroll
    for (int m = 0; m < 4; ++m) {
      const int r = wr * 64 + m * 16 + fr;
      a[m] = *(const long2v*)&lA[r * BK + ((g ^ (fr & 3)) << 4)];
    }
#pragma unroll
    for (int n = 0; n < 4; ++n) {
      const int r = wc * 64 + n * 16 + fr;
      b[n] = *(const long2v*)&lB[r * BK + ((g ^ (fr & 3)) << 4)];
    }
#pragma unroll
    for (int ks = 0; ks < 2; ++ks)
#pragma unroll
      for (int m = 0; m < 4; ++m)
#pragma unroll
        for (int n = 0; n < 4; ++n)
          acc[m][n] = __builtin_amdgcn_mfma_f32_16x16x32_fp8_fp8(
              a[m][ks], b[n][ks], acc[m][n], 0, 0, 0);
    __syncthreads();
  }

  // epilogue: C/D layout col=lane&15, row=(lane>>4)*4+i (dtype-independent)
  const int r4 = (lane >> 4) * 4;
#pragma unroll
  for (int m = 0; m < 4; ++m) {
#pragma unroll
    for (int n = 0; n < 4; ++n) {
      const int c = col0 + wc * 64 + n * 16 + fr;
      const float wsn = ws[c];
      const float bb = bias[c];
#pragma unroll
      for (int i = 0; i < 4; ++i) {
        const int r = row0 + wr * 64 + m * 16 + r4 + i;
        C[(size_t)r * N + c] = acc[m][n][i] * xs[r] * wsn + bb;
      }
    }
  }
}

extern "C" void kernel_launch(void* const* d_in, const int* in_sizes, int n_in,
                              void* d_out, int out_size, void* d_ws, size_t ws_size,
                              hipStream_t stream) {
  const float* input = (const float*)d_in[0];   // [M,K] fp32
  const float* weight = (const float*)d_in[1];  // [N,K] fp32
  const float* bias = (const float*)d_in[2];    // [N]   fp32
  float* out = (float*)d_out;                   // [M,N] fp32

  const int K = 4096;
  const int N = in_sizes[2];
  const int M = in_sizes[0] / K;

  // workspace layout: qA[M*K] | qW[N*K] | xs[M] | ws[N]  (~50.4 MB)
  uint8_t* qA = (uint8_t*)d_ws;
  uint8_t* qW = qA + (size_t)M * K;
  float* xsc = (float*)(qW + (size_t)N * K);
  float* wsc = xsc + M;

  quant_rowwise<<<M, 256, 0, stream>>>(input, qA, xsc, K);
  quant_rowwise<<<N, 256, 0, stream>>>(weight, qW, wsc, K);

  dim3 grid(M / BM, N / BN);
  gemm_fp8<<<grid, 256, 0, stream>>>(qA, qW, xsc, wsc, bias, out, M, N, K);
}

// Round 3
// 259.782 us; speedup vs baseline: 1.5171x; 1.0925x over previous
//
#include <hip/hip_runtime.h>
#include <cstdint>
#include <cstddef>

typedef float f32x4 __attribute__((ext_vector_type(4)));
typedef long long2v __attribute__((ext_vector_type(2)));

#define FP8_MAX 448.0f

// async global->LDS, 16B per lane; LDS dest is wave-uniform base + lane*16
#define GL(gp, lp)                                               \
  __builtin_amdgcn_global_load_lds(                              \
      (const __attribute__((address_space(1))) void*)(gp),       \
      (__attribute__((address_space(3))) void*)(lp), 16, 0, 0)

__device__ __forceinline__ uint32_t pack4_e4m3(float a, float b, float c, float d) {
  int p = __builtin_amdgcn_cvt_pk_fp8_f32(a, b, 0, false);
  p = __builtin_amdgcn_cvt_pk_fp8_f32(c, d, p, true);
  return (uint32_t)p;
}

// One block (256 threads) per row of K=4096 fp32.
__global__ __launch_bounds__(256) void quant_rowwise(
    const float* __restrict__ X, uint8_t* __restrict__ Q,
    float* __restrict__ recip, int K) {
  const int row = blockIdx.x;
  const int tid = threadIdx.x;
  const float4* __restrict__ x4 = (const float4*)(X + (size_t)row * K);
  float4 v[4];
  float am = 0.0f;
#pragma unroll
  for (int i = 0; i < 4; ++i) {
    v[i] = x4[i * 256 + tid];
    am = fmaxf(am, fmaxf(fmaxf(fabsf(v[i].x), fabsf(v[i].y)),
                         fmaxf(fabsf(v[i].z), fabsf(v[i].w))));
  }
#pragma unroll
  for (int off = 32; off > 0; off >>= 1)
    am = fmaxf(am, __shfl_xor(am, off));
  __shared__ float smax[4];
  const int wave = tid >> 6, lane = tid & 63;
  if (lane == 0) smax[wave] = am;
  __syncthreads();
  am = fmaxf(fmaxf(smax[0], smax[1]), fmaxf(smax[2], smax[3]));
  am = fmaxf(am, 1e-12f);
  const float scale = FP8_MAX / am;
  if (tid == 0) recip[row] = 1.0f / scale;
  uint32_t* __restrict__ q32 = (uint32_t*)(Q + (size_t)row * K);
#pragma unroll
  for (int i = 0; i < 4; ++i) {
    float a = fminf(fmaxf(v[i].x * scale, -FP8_MAX), FP8_MAX);
    float b = fminf(fmaxf(v[i].y * scale, -FP8_MAX), FP8_MAX);
    float c = fminf(fmaxf(v[i].z * scale, -FP8_MAX), FP8_MAX);
    float d = fminf(fmaxf(v[i].w * scale, -FP8_MAX), FP8_MAX);
    q32[i * 256 + tid] = pack4_e4m3(a, b, c, d);
  }
}

// ---------------------------------------------------------------------------
// 256x256 tile, 8 waves (2 Mx4 N), BK=64 bytes, 8-phase-style counted-vmcnt
// schedule (4 phases per K-tile), double-buffered 64 KiB LDS.
// Per wave output: 128x64 = acc[8][4] f32x4.
// LDS rows are 64 B (4 chunks of 16B); chunk swizzle: stored[r][c] =
// logical[r][c ^ (r&3)], applied on the pre-swizzled GLOBAL source (staging)
// and on the ds_read chunk index (rule #21 both-sides).
// k-permuted ds_read_b128: lane-group g reads logical chunk g; its 8B halves
// are the operands of MFMA invocations ks=0,1 (same mapping for A and B).
// ---------------------------------------------------------------------------

#define LDA(m) (*(const long2v*)&lds[curA + (m) * 1024])
#define LDB(n) (*(const long2v*)&lds[curB + (n) * 1024])

#define MM(M, N, A, B)                                                        \
  acc[M][N] = __builtin_amdgcn_mfma_f32_16x16x32_fp8_fp8((A)[0], (B)[0],      \
                                                         acc[M][N], 0, 0, 0); \
  acc[M][N] = __builtin_amdgcn_mfma_f32_16x16x32_fp8_fp8((A)[1], (B)[1],      \
                                                         acc[M][N], 0, 0, 0);

// stage half-tile h (0:A rows 0-127, 1:A 128-255, 2:B 0-127, 3:B 128-255)
// of K-tile kt1 into buffer nb. One global_load_lds (16B/lane) per wave.
#define STAGE(h, kt1, nb)                                                     \
  do {                                                                        \
    const uint8_t* sp =                                                       \
        ((h) < 2 ? Aq + aoff + (size_t)(h) * 128 * K                          \
                 : Bq + boff + (size_t)((h) - 2) * 128 * K) +                 \
        (size_t)(kt1) * 64;                                                   \
    GL(sp, &lds[((h) < 2 ? 0 : 32768) + (nb) * 16384 + ((h) & 1) * 8192 +    \
                w * 1024]);                                                   \
  } while (0)

__global__ __launch_bounds__(512, 1) void gemm_fp8(
    const uint8_t* __restrict__ Aq, const uint8_t* __restrict__ Bq,
    const float* __restrict__ xs, const float* __restrict__ ws,
    const float* __restrict__ bias, float* __restrict__ C,
    int M, int N, int K) {
  __shared__ __align__(16) uint8_t lds[65536];
  const int tid = threadIdx.x;
  const int w = tid >> 6, lane = tid & 63;
  const int wrow = w >> 2, wcol = w & 3;

  // XCD-aware bijective swizzle: 512 WGs, 8 XCDs, 64 per XCD.
  int bid = (int)blockIdx.x;
  bid = (bid & 7) * 64 + (bid >> 3);
  const int bm = bid & 31, bn = bid >> 5;
  const int row0 = bm * 256, col0 = bn * 256;

  const int fr = lane & 15, g = lane >> 4;

  // staging per-lane source offsets (pre-swizzled logical chunk)
  const int srow = lane >> 2;                              // row in 16-row strip
  const int scol = 16 * ((lane & 3) ^ (srow & 3));         // logical byte col
  const size_t aoff = (size_t)(row0 + 16 * w + srow) * K + scol;
  const size_t boff = (size_t)(col0 + 16 * w + srow) * K + scol;

  // ds_read per-lane base offsets (swizzled chunk)
  const int chunk = 16 * (g ^ (fr & 3));
  const int base_rA = (wrow * 128 + fr) * 64 + chunk;
  const int base_rB = (wcol * 64 + fr) * 64 + chunk;

  f32x4 acc[8][4];
#pragma unroll
  for (int m = 0; m < 8; ++m)
#pragma unroll
    for (int n = 0; n < 4; ++n) acc[m][n] = {0.f, 0.f, 0.f, 0.f};

  const int nk = K / 64;

  // prologue: stage K-tile 0 into buf 0
  STAGE(0, 0, 0);
  STAGE(1, 0, 0);
  STAGE(2, 0, 0);
  STAGE(3, 0, 0);

  for (int t = 0; t < nk; ++t) {
    const int cur = t & 1, nb = cur ^ 1;
    const int kt1 = (t + 1 < nk) ? t + 1 : t;  // clamped prefetch (dead buf at tail)
    const int curA = cur * 16384 + base_rA;
    const int curB = 32768 + cur * 16384 + base_rB;
    long2v a0, a1, a2, a3, a4, a5, a6, a7, b0, b1, b2, b3;

    // ---- phase 0: Q(0,0)  [tile-boundary gate: counted vmcnt, no drain]
    STAGE(0, kt1, nb);
    asm volatile("s_waitcnt vmcnt(1)" ::: "memory");
    __builtin_amdgcn_s_barrier();
    a0 = LDA(0); a1 = LDA(1); a2 = LDA(2); a3 = LDA(3);
    b0 = LDB(0); b1 = LDB(1);
    asm volatile("s_waitcnt lgkmcnt(0)" ::: "memory");
    __builtin_amdgcn_s_setprio(1);
    MM(0, 0, a0, b0) MM(1, 0, a1, b0) MM(2, 0, a2, b0) MM(3, 0, a3, b0)
    MM(0, 1, a0, b1) MM(1, 1, a1, b1) MM(2, 1, a2, b1) MM(3, 1, a3, b1)
    __builtin_amdgcn_s_setprio(0);
    __builtin_amdgcn_s_barrier();

    // ---- phase 1: Q(0,1)  (A0-3 reused)
    b2 = LDB(2); b3 = LDB(3);
    STAGE(1, kt1, nb);
    __builtin_amdgcn_s_barrier();
    asm volatile("s_waitcnt lgkmcnt(0)" ::: "memory");
    __builtin_amdgcn_s_setprio(1);
    MM(0, 2, a0, b2) MM(1, 2, a1, b2) MM(2, 2, a2, b2) MM(3, 2, a3, b2)
    MM(0, 3, a0, b3) MM(1, 3, a1, b3) MM(2, 3, a2, b3) MM(3, 3, a3, b3)
    __builtin_amdgcn_s_setprio(0);
    __builtin_amdgcn_s_barrier();

    // ---- phase 2: Q(1,0)  (B0-1 reused)
    a4 = LDA(4); a5 = LDA(5); a6 = LDA(6); a7 = LDA(7);
    STAGE(2, kt1, nb);
    __builtin_amdgcn_s_barrier();
    asm volatile("s_waitcnt lgkmcnt(0)" ::: "memory");
    __builtin_amdgcn_s_setprio(1);
    MM(4, 0, a4, b0) MM(5, 0, a5, b0) MM(6, 0, a6, b0) MM(7, 0, a7, b0)
    MM(4, 1, a4, b1) MM(5, 1, a5, b1) MM(6, 1, a6, b1) MM(7, 1, a7, b1)
    __builtin_amdgcn_s_setprio(0);
    __builtin_amdgcn_s_barrier();

    // ---- phase 3: Q(1,1)  (A4-7, B2-3 reused; no ds_reads)
    STAGE(3, kt1, nb);
    __builtin_amdgcn_s_barrier();
    __builtin_amdgcn_s_setprio(1);
    MM(4, 2, a4, b2) MM(5, 2, a5, b2) MM(6, 2, a6, b2) MM(7, 2, a7, b2)
    MM(4, 3, a4, b3) MM(5, 3, a5, b3) MM(6, 3, a6, b3) MM(7, 3, a7, b3)
    __builtin_amdgcn_s_setprio(0);
    __builtin_amdgcn_s_barrier();
  }

  // epilogue: C/D layout col=lane&15, row=(lane>>4)*4+i
  const int r4 = (lane >> 4) * 4;
#pragma unroll
  for (int m = 0; m < 8; ++m) {
#pragma unroll
    for (int n = 0; n < 4; ++n) {
      const int c = col0 + wcol * 64 + n * 16 + fr;
      const float wsn = ws[c];
      const float bb = bias[c];
#pragma unroll
      for (int i = 0; i < 4; ++i) {
        const int r = row0 + wrow * 128 + m * 16 + r4 + i;
        C[(size_t)r * N + c] = acc[m][n][i] * xs[r] * wsn + bb;
      }
    }
  }
}

extern "C" void kernel_launch(void* const* d_in, const int* in_sizes, int n_in,
                              void* d_out, int out_size, void* d_ws, size_t ws_size,
                              hipStream_t stream) {
  const float* input = (const float*)d_in[0];   // [M,K] fp32
  const float* weight = (const float*)d_in[1];  // [N,K] fp32
  const float* bias = (const float*)d_in[2];    // [N]   fp32
  float* out = (float*)d_out;                   // [M,N] fp32

  const int K = 4096;
  const int N = in_sizes[2];
  const int M = in_sizes[0] / K;

  uint8_t* qA = (uint8_t*)d_ws;
  uint8_t* qW = qA + (size_t)M * K;
  float* xsc = (float*)(qW + (size_t)N * K);
  float* wsc = xsc + M;

  quant_rowwise<<<M, 256, 0, stream>>>(input, qA, xsc, K);
  quant_rowwise<<<N, 256, 0, stream>>>(weight, qW, wsc, K);

  dim3 grid((M / 256) * (N / 256));
  gemm_fp8<<<grid, 512, 0, stream>>>(qA, qW, xsc, wsc, bias, out, M, N, K);
}

// Round 4
// 254.760 us; speedup vs baseline: 1.5470x; 1.0197x over previous
//
#include <hip/hip_runtime.h>
#include <cstdint>
#include <cstddef>

typedef float f32x4 __attribute__((ext_vector_type(4)));
typedef long long2v __attribute__((ext_vector_type(2)));

#define FP8_MAX 448.0f

// async global->LDS, 16B per lane; LDS dest is wave-uniform base + lane*16
#define GL(gp, lp)                                               \
  __builtin_amdgcn_global_load_lds(                              \
      (const __attribute__((address_space(1))) void*)(gp),       \
      (__attribute__((address_space(3))) void*)(lp), 16, 0, 0)

__device__ __forceinline__ uint32_t pack4_e4m3(float a, float b, float c, float d) {
  int p = __builtin_amdgcn_cvt_pk_fp8_f32(a, b, 0, false);
  p = __builtin_amdgcn_cvt_pk_fp8_f32(c, d, p, true);
  return (uint32_t)p;
}

// Fused rowwise quant: blocks [0,M) quantize input rows, [M,M+N) weight rows.
__global__ __launch_bounds__(256) void quant_rowwise(
    const float* __restrict__ X, const float* __restrict__ W,
    uint8_t* __restrict__ QA, uint8_t* __restrict__ QW,
    float* __restrict__ xsc, float* __restrict__ wsc, int K, int M) {
  const int row = blockIdx.x;
  const float* src;
  uint8_t* q;
  float* rec;
  if (row < M) {
    src = X + (size_t)row * K; q = QA + (size_t)row * K; rec = xsc + row;
  } else {
    const int r = row - M;
    src = W + (size_t)r * K; q = QW + (size_t)r * K; rec = wsc + r;
  }
  const int tid = threadIdx.x;
  const float4* __restrict__ x4 = (const float4*)src;
  float4 v[4];
  float am = 0.0f;
#pragma unroll
  for (int i = 0; i < 4; ++i) {
    v[i] = x4[i * 256 + tid];
    am = fmaxf(am, fmaxf(fmaxf(fabsf(v[i].x), fabsf(v[i].y)),
                         fmaxf(fabsf(v[i].z), fabsf(v[i].w))));
  }
#pragma unroll
  for (int off = 32; off > 0; off >>= 1)
    am = fmaxf(am, __shfl_xor(am, off));
  __shared__ float smax[4];
  const int wave = tid >> 6, lane = tid & 63;
  if (lane == 0) smax[wave] = am;
  __syncthreads();
  am = fmaxf(fmaxf(smax[0], smax[1]), fmaxf(smax[2], smax[3]));
  am = fmaxf(am, 1e-12f);
  const float scale = FP8_MAX / am;  // exact IEEE div (no fast-math)
  if (tid == 0) rec[0] = 1.0f / scale;
  uint32_t* __restrict__ q32 = (uint32_t*)q;
#pragma unroll
  for (int i = 0; i < 4; ++i) {
    float a = fminf(fmaxf(v[i].x * scale, -FP8_MAX), FP8_MAX);
    float b = fminf(fmaxf(v[i].y * scale, -FP8_MAX), FP8_MAX);
    float c = fminf(fmaxf(v[i].z * scale, -FP8_MAX), FP8_MAX);
    float d = fminf(fmaxf(v[i].w * scale, -FP8_MAX), FP8_MAX);
    q32[i * 256 + tid] = pack4_e4m3(a, b, c, d);
  }
}

// ---------------------------------------------------------------------------
// 256x256 tile, 8 waves (2M x 4N), BK=64 bytes, 4 phases/K-tile, counted
// vmcnt, TRIPLE-buffered LDS (96 KiB), prefetch distance = 2 K-tiles
// (one STAGE issue per phase; gate vmcnt(4) once per K-tile -> the 4 loads
// for tile t+1 stay in flight across the gate; ~5 phases of slack per load).
// Per wave output: 128x64 = acc[8][4] f32x4.
// LDS rows 64 B (4 x 16B chunks); swizzle stored[r][c]=logical[r][c^(r&3)],
// applied on the pre-swizzled GLOBAL source and the ds_read chunk (rule #21).
// k-permuted ds_read_b128: lane-group g reads logical chunk g; 8B halves
// feed MFMA k-slots ks=0,1 (same mapping for A and B -> k-sum commutes).
// ---------------------------------------------------------------------------

#define LDA(m) (*(const long2v*)&lds[curA + (m) * 1024])
#define LDB(n) (*(const long2v*)&lds[curB + (n) * 1024])

#define MM(M, N, A, B)                                                        \
  acc[M][N] = __builtin_amdgcn_mfma_f32_16x16x32_fp8_fp8((A)[0], (B)[0],      \
                                                         acc[M][N], 0, 0, 0); \
  acc[M][N] = __builtin_amdgcn_mfma_f32_16x16x32_fp8_fp8((A)[1], (B)[1],      \
                                                         acc[M][N], 0, 0, 0);

// stage half-tile h (0:A rows 0-127, 1:A 128-255, 2:B 0-127, 3:B 128-255)
// of K-tile kt into buffer bi (0..2). One global_load_lds (16B/lane) per wave.
#define STAGE(h, kt, bi)                                                      \
  do {                                                                        \
    const uint8_t* sp =                                                       \
        ((h) < 2 ? Aq + aoff + (size_t)(h) * 128 * K                          \
                 : Bq + boff + (size_t)((h) - 2) * 128 * K) +                 \
        (size_t)(kt) * 64;                                                    \
    GL(sp, &lds[((h) < 2 ? 0 : 49152) + (bi) * 16384 + ((h) & 1) * 8192 +    \
                w * 1024]);                                                   \
  } while (0)

__global__ __launch_bounds__(512, 1) void gemm_fp8(
    const uint8_t* __restrict__ Aq, const uint8_t* __restrict__ Bq,
    const float* __restrict__ xs, const float* __restrict__ wsc,
    const float* __restrict__ bias, float* __restrict__ C,
    int M, int N, int K) {
  __shared__ __align__(16) uint8_t lds[98304];
  const int tid = threadIdx.x;
  const int w = tid >> 6, lane = tid & 63;
  const int wrow = w >> 2, wcol = w & 3;

  // XCD-aware bijective swizzle: 512 WGs, 8 XCDs, 64 per XCD.
  int bid = (int)blockIdx.x;
  bid = (bid & 7) * 64 + (bid >> 3);
  const int bm = bid & 31, bn = bid >> 5;
  const int row0 = bm * 256, col0 = bn * 256;

  const int fr = lane & 15, g = lane >> 4;

  // staging per-lane source offsets (pre-swizzled logical chunk)
  const int srow = lane >> 2;                       // row in 16-row strip
  const int scol = 16 * ((lane & 3) ^ (srow & 3));  // logical byte col
  const size_t aoff = (size_t)(row0 + 16 * w + srow) * K + scol;
  const size_t boff = (size_t)(col0 + 16 * w + srow) * K + scol;

  // ds_read per-lane base offsets (swizzled chunk)
  const int chunk = 16 * (g ^ (fr & 3));
  const int base_rA = (wrow * 128 + fr) * 64 + chunk;
  const int base_rB = (wcol * 64 + fr) * 64 + chunk;

  f32x4 acc[8][4];
#pragma unroll
  for (int m = 0; m < 8; ++m)
#pragma unroll
    for (int n = 0; n < 4; ++n) acc[m][n] = {0.f, 0.f, 0.f, 0.f};

  const int nk = K / 64;

  // prologue: stage K-tiles 0 and 1 into buffers 0 and 1
  STAGE(0, 0, 0); STAGE(1, 0, 0); STAGE(2, 0, 0); STAGE(3, 0, 0);
  STAGE(0, 1, 1); STAGE(1, 1, 1); STAGE(2, 1, 1); STAGE(3, 1, 1);

  for (int t = 0; t < nk; ++t) {
    const int bi = t % 3;
    const int pb = (t + 2) % 3;
    const int pf = (t + 2 < nk) ? t + 2 : t;  // clamped tail prefetch (dead)
    const int curA = bi * 16384 + base_rA;
    const int curB = 49152 + bi * 16384 + base_rB;
    long2v a0, a1, a2, a3, a4, a5, a6, a7, b0, b1, b2, b3;

    // ---- phase 0: Q(0,0)  [tile gate: counted vmcnt, never a drain]
    asm volatile("s_waitcnt vmcnt(4)" ::: "memory");
    __builtin_amdgcn_s_barrier();
    STAGE(0, pf, pb);
    a0 = LDA(0); a1 = LDA(1); a2 = LDA(2); a3 = LDA(3);
    b0 = LDB(0); b1 = LDB(1);
    asm volatile("s_waitcnt lgkmcnt(0)" ::: "memory");
    __builtin_amdgcn_s_setprio(1);
    MM(0, 0, a0, b0) MM(1, 0, a1, b0) MM(2, 0, a2, b0) MM(3, 0, a3, b0)
    MM(0, 1, a0, b1) MM(1, 1, a1, b1) MM(2, 1, a2, b1) MM(3, 1, a3, b1)
    __builtin_amdgcn_s_setprio(0);
    __builtin_amdgcn_s_barrier();

    // ---- phase 1: Q(0,1)  (A0-3 reused)
    b2 = LDB(2); b3 = LDB(3);
    STAGE(1, pf, pb);
    __builtin_amdgcn_s_barrier();
    asm volatile("s_waitcnt lgkmcnt(0)" ::: "memory");
    __builtin_amdgcn_s_setprio(1);
    MM(0, 2, a0, b2) MM(1, 2, a1, b2) MM(2, 2, a2, b2) MM(3, 2, a3, b2)
    MM(0, 3, a0, b3) MM(1, 3, a1, b3) MM(2, 3, a2, b3) MM(3, 3, a3, b3)
    __builtin_amdgcn_s_setprio(0);
    __builtin_amdgcn_s_barrier();

    // ---- phase 2: Q(1,0)  (B0-1 reused)
    a4 = LDA(4); a5 = LDA(5); a6 = LDA(6); a7 = LDA(7);
    STAGE(2, pf, pb);
    __builtin_amdgcn_s_barrier();
    asm volatile("s_waitcnt lgkmcnt(0)" ::: "memory");
    __builtin_amdgcn_s_setprio(1);
    MM(4, 0, a4, b0) MM(5, 0, a5, b0) MM(6, 0, a6, b0) MM(7, 0, a7, b0)
    MM(4, 1, a4, b1) MM(5, 1, a5, b1) MM(6, 1, a6, b1) MM(7, 1, a7, b1)
    __builtin_amdgcn_s_setprio(0);
    __builtin_amdgcn_s_barrier();

    // ---- phase 3: Q(1,1)  (A4-7, B2-3 reused; no ds_reads)
    STAGE(3, pf, pb);
    __builtin_amdgcn_s_barrier();
    __builtin_amdgcn_s_setprio(1);
    MM(4, 2, a4, b2) MM(5, 2, a5, b2) MM(6, 2, a6, b2) MM(7, 2, a7, b2)
    MM(4, 3, a4, b3) MM(5, 3, a5, b3) MM(6, 3, a6, b3) MM(7, 3, a7, b3)
    __builtin_amdgcn_s_setprio(0);
    __builtin_amdgcn_s_barrier();
  }

  // epilogue: C/D layout col=lane&15, row=(lane>>4)*4+i
  const int r4 = (lane >> 4) * 4;
#pragma unroll
  for (int m = 0; m < 8; ++m) {
#pragma unroll
    for (int n = 0; n < 4; ++n) {
      const int c = col0 + wcol * 64 + n * 16 + fr;
      const float wsn = wsc[c];
      const float bb = bias[c];
#pragma unroll
      for (int i = 0; i < 4; ++i) {
        const int r = row0 + wrow * 128 + m * 16 + r4 + i;
        C[(size_t)r * N + c] = acc[m][n][i] * xs[r] * wsn + bb;
      }
    }
  }
}

extern "C" void kernel_launch(void* const* d_in, const int* in_sizes, int n_in,
                              void* d_out, int out_size, void* d_ws, size_t ws_size,
                              hipStream_t stream) {
  const float* input = (const float*)d_in[0];   // [M,K] fp32
  const float* weight = (const float*)d_in[1];  // [N,K] fp32
  const float* bias = (const float*)d_in[2];    // [N]   fp32
  float* out = (float*)d_out;                   // [M,N] fp32

  const int K = 4096;
  const int N = in_sizes[2];
  const int M = in_sizes[0] / K;

  uint8_t* qA = (uint8_t*)d_ws;
  uint8_t* qW = qA + (size_t)M * K;
  float* xsc = (float*)(qW + (size_t)N * K);
  float* wsc = xsc + M;

  quant_rowwise<<<M + N, 256, 0, stream>>>(input, weight, qA, qW, xsc, wsc, K, M);

  dim3 grid((M / 256) * (N / 256));
  gemm_fp8<<<grid, 512, 0, stream>>>(qA, qW, xsc, wsc, bias, out, M, N, K);
}

// Round 5
// 191.656 us; speedup vs baseline: 2.0564x; 1.3293x over previous
//
#include <hip/hip_runtime.h>
#include <cstdint>
#include <cstddef>

typedef float f32x16 __attribute__((ext_vector_type(16)));
typedef int i32x4 __attribute__((ext_vector_type(4)));
typedef int i32x8 __attribute__((ext_vector_type(8)));

#define FP8_MAX 448.0f

// async global->LDS, 16B per lane; LDS dest is wave-uniform base + lane*16
#define GL(gp, lp)                                               \
  __builtin_amdgcn_global_load_lds(                              \
      (const __attribute__((address_space(1))) void*)(gp),       \
      (__attribute__((address_space(3))) void*)(lp), 16, 0, 0)

__device__ __forceinline__ uint32_t pack4_e4m3(float a, float b, float c, float d) {
  int p = __builtin_amdgcn_cvt_pk_fp8_f32(a, b, 0, false);
  p = __builtin_amdgcn_cvt_pk_fp8_f32(c, d, p, true);
  return (uint32_t)p;
}

// Fused rowwise quant: blocks [0,M) quantize input rows, [M,M+N) weight rows.
__global__ __launch_bounds__(256) void quant_rowwise(
    const float* __restrict__ X, const float* __restrict__ W,
    uint8_t* __restrict__ QA, uint8_t* __restrict__ QW,
    float* __restrict__ xsc, float* __restrict__ wsc, int K, int M) {
  const int row = blockIdx.x;
  const float* src;
  uint8_t* q;
  float* rec;
  if (row < M) {
    src = X + (size_t)row * K; q = QA + (size_t)row * K; rec = xsc + row;
  } else {
    const int r = row - M;
    src = W + (size_t)r * K; q = QW + (size_t)r * K; rec = wsc + r;
  }
  const int tid = threadIdx.x;
  const float4* __restrict__ x4 = (const float4*)src;
  float4 v[4];
  float am = 0.0f;
#pragma unroll
  for (int i = 0; i < 4; ++i) {
    v[i] = x4[i * 256 + tid];
    am = fmaxf(am, fmaxf(fmaxf(fabsf(v[i].x), fabsf(v[i].y)),
                         fmaxf(fabsf(v[i].z), fabsf(v[i].w))));
  }
#pragma unroll
  for (int off = 32; off > 0; off >>= 1)
    am = fmaxf(am, __shfl_xor(am, off));
  __shared__ float smax[4];
  const int wave = tid >> 6, lane = tid & 63;
  if (lane == 0) smax[wave] = am;
  __syncthreads();
  am = fmaxf(fmaxf(smax[0], smax[1]), fmaxf(smax[2], smax[3]));
  am = fmaxf(am, 1e-12f);
  const float scale = FP8_MAX / am;  // exact IEEE div (no fast-math)
  if (tid == 0) rec[0] = 1.0f / scale;
  uint32_t* __restrict__ q32 = (uint32_t*)q;
#pragma unroll
  for (int i = 0; i < 4; ++i) {
    float a = fminf(fmaxf(v[i].x * scale, -FP8_MAX), FP8_MAX);
    float b = fminf(fmaxf(v[i].y * scale, -FP8_MAX), FP8_MAX);
    float c = fminf(fmaxf(v[i].z * scale, -FP8_MAX), FP8_MAX);
    float d = fminf(fmaxf(v[i].w * scale, -FP8_MAX), FP8_MAX);
    q32[i * 256 + tid] = pack4_e4m3(a, b, c, d);
  }
}

// ---------------------------------------------------------------------------
// MX-scaled fp8 GEMM at 2x rate: mfma_scale_f32_32x32x64_f8f6f4 with all
// E8M0 scales = 1.0 (0x7F) == exact fp8 e4m3 matmul (only fp32 sum order
// differs from the non-scaled path).
// 256x256 tile, 8 waves (2M x 4N), BK=64 bytes = one MFMA-K. ONE phase per
// K-tile: {vmcnt(4) gate, s_barrier, 12x ds_read_b128, 4x STAGE(t+2),
// setprio(1), 8x MFMA, setprio(0)}. Triple-buffered LDS (3 x 32 KiB),
// prefetch distance 2, counted gate (never drains).
// Fragment layout (extends verified 16x16x32 pattern): A/B lane l holds
// row/col = l&31, k = 32*(l>>5) + byte(0..31). C/D 32x32: col = l&31,
// row = (reg&3) + 8*(reg>>2) + 4*(l>>5)  [m74/m101, dtype-independent].
// LDS swizzle: stored[r][c] = logical[r][c ^ ((r>>1)&3)] (16B chunks),
// applied to pre-swizzled GLOBAL source AND ds_read chunk (rule #21).
// Read-uniformity: slot(r) = 64*(r&1) + 16*(c^((r>>1)&3)) is bijective on
// r mod 8 -> 8 slots x 8 lanes = conflict-free b128 reads.
// ---------------------------------------------------------------------------

#define MMS(TM, TN, A, B)                                          \
  acc[TM][TN] = __builtin_amdgcn_mfma_scale_f32_32x32x64_f8f6f4(   \
      (A), (B), acc[TM][TN], 0, 0, 0, 0x7F7F7F7F, 0, 0x7F7F7F7F);

// stage half-tile h (0:A rows 0-127, 1:A rows 128-255, 2:B 0-127, 3:B 128-255)
// of K-tile kt into buffer bi (0..2). One global_load_lds (16B/lane) per wave.
#define STAGE(h, kt, bi)                                                    \
  do {                                                                      \
    const uint8_t* sp = ((h) < 2 ? Aq + aoff : Bq + boff) +                 \
                        (size_t)((h) & 1) * 128 * K + (size_t)(kt) * 64;    \
    GL(sp, &lds[(bi) * 32768 + ((h) < 2 ? 0 : 16384) + ((h) & 1) * 8192 +  \
                w * 1024]);                                                 \
  } while (0)

__device__ __forceinline__ i32x8 ldfrag(const uint8_t* p, int off) {
  i32x4 lo = *(const i32x4*)(p + off);         // logical k-bytes 0-15
  i32x4 hi = *(const i32x4*)(p + (off ^ 16));  // logical k-bytes 16-31
  return __builtin_shufflevector(lo, hi, 0, 1, 2, 3, 4, 5, 6, 7);
}

__global__ __launch_bounds__(512, 1) void gemm_fp8(
    const uint8_t* __restrict__ Aq, const uint8_t* __restrict__ Bq,
    const float* __restrict__ xs, const float* __restrict__ wsc,
    const float* __restrict__ bias, float* __restrict__ C,
    int M, int N, int K) {
  __shared__ __align__(16) uint8_t lds[98304];
  const int tid = threadIdx.x;
  const int w = tid >> 6, lane = tid & 63;
  const int wrow = w >> 2, wcol = w & 3;

  // XCD-aware bijective swizzle: 512 WGs, 8 XCDs, 64 per XCD.
  int bid = (int)blockIdx.x;
  bid = (bid & 7) * 64 + (bid >> 3);
  const int bm = bid & 31, bn = bid >> 5;
  const int row0 = bm * 256, col0 = bn * 256;

  // staging per-lane source offsets (pre-swizzled logical chunk):
  // lane l feeds stored slot (srow = l>>2, l&3); logical chunk = (l&3)^h,
  // h = bits 1,2 of row = (l>>3)&3.
  const int srow = lane >> 2;
  const int scol = 16 * ((lane & 3) ^ ((lane >> 3) & 3));
  const size_t aoff = (size_t)(row0 + 16 * w + srow) * K + scol;
  const size_t boff = (size_t)(col0 + 16 * w + srow) * K + scol;

  // ds_read per-lane base offsets: row r = (base)+(lane&31); lane's first
  // logical chunk = 2*(lane>>5); stored chunk = logical ^ ((r>>1)&3).
  const int ln31 = lane & 31;
  const int g2 = (lane >> 5) * 2;
  const int h = (ln31 >> 1) & 3;
  const int o0 = 16 * (g2 ^ h);
  const int arow = (wrow * 128 + ln31) * 64 + o0;   // + tm*2048
  const int brow = (wcol * 64 + ln31) * 64 + o0;    // + tn*2048

  f32x16 zero = {};
  f32x16 acc[4][2];
#pragma unroll
  for (int m = 0; m < 4; ++m)
#pragma unroll
    for (int n = 0; n < 2; ++n) acc[m][n] = zero;

  const int nk = K / 64;

  // prologue: K-tile 0 -> buf 0, K-tile 1 -> buf 1
  STAGE(0, 0, 0); STAGE(1, 0, 0); STAGE(2, 0, 0); STAGE(3, 0, 0);
  STAGE(0, 1, 1); STAGE(1, 1, 1); STAGE(2, 1, 1); STAGE(3, 1, 1);

  for (int t = 0; t < nk; ++t) {
    const int bi = t % 3;
    const int pb = (t + 2) % 3;
    const int pf = (t + 2 < nk) ? t + 2 : t;  // clamped tail prefetch (dead)
    const int bA = bi * 32768;
    const int bB = bA + 16384;

    // gate: own 4 loads for tile t done; t+1's 4 stay in flight.
    asm volatile("s_waitcnt vmcnt(4)" ::: "memory");
    __builtin_amdgcn_s_barrier();

    i32x8 a0 = ldfrag(lds, bA + arow);
    i32x8 b0 = ldfrag(lds, bB + brow);
    i32x8 b1 = ldfrag(lds, bB + brow + 2048);
    i32x8 a1 = ldfrag(lds, bA + arow + 2048);
    i32x8 a2 = ldfrag(lds, bA + arow + 4096);
    i32x8 a3 = ldfrag(lds, bA + arow + 6144);

    STAGE(0, pf, pb); STAGE(1, pf, pb); STAGE(2, pf, pb); STAGE(3, pf, pb);

    __builtin_amdgcn_s_setprio(1);
    MMS(0, 0, a0, b0) MMS(0, 1, a0, b1)
    MMS(1, 0, a1, b0) MMS(1, 1, a1, b1)
    MMS(2, 0, a2, b0) MMS(2, 1, a2, b1)
    MMS(3, 0, a3, b0) MMS(3, 1, a3, b1)
    __builtin_amdgcn_s_setprio(0);
  }

  // epilogue: C/D 32x32 layout col=lane&31, row=(reg&3)+8*(reg>>2)+4*(lane>>5)
  const int cl = lane & 31;
  const int rtop = (lane >> 5) * 4;
#pragma unroll
  for (int tm = 0; tm < 4; ++tm) {
#pragma unroll
    for (int tn = 0; tn < 2; ++tn) {
      const int col = col0 + wcol * 64 + tn * 32 + cl;
      const float wsn = wsc[col];
      const float bb = bias[col];
      const int rowb = row0 + wrow * 128 + tm * 32 + rtop;
#pragma unroll
      for (int q = 0; q < 4; ++q) {
        const float4 xq = *(const float4*)&xs[rowb + 8 * q];
        const float xa[4] = {xq.x, xq.y, xq.z, xq.w};
#pragma unroll
        for (int j = 0; j < 4; ++j) {
          const int r = rowb + 8 * q + j;
          C[(size_t)r * N + col] = fmaf(acc[tm][tn][4 * q + j] * xa[j], wsn, bb);
        }
      }
    }
  }
}

extern "C" void kernel_launch(void* const* d_in, const int* in_sizes, int n_in,
                              void* d_out, int out_size, void* d_ws, size_t ws_size,
                              hipStream_t stream) {
  const float* input = (const float*)d_in[0];   // [M,K] fp32
  const float* weight = (const float*)d_in[1];  // [N,K] fp32
  const float* bias = (const float*)d_in[2];    // [N]   fp32
  float* out = (float*)d_out;                   // [M,N] fp32

  const int K = 4096;
  const int N = in_sizes[2];
  const int M = in_sizes[0] / K;

  uint8_t* qA = (uint8_t*)d_ws;
  uint8_t* qW = qA + (size_t)M * K;
  float* xsc = (float*)(qW + (size_t)N * K);
  float* wsc = xsc + M;

  quant_rowwise<<<M + N, 256, 0, stream>>>(input, weight, qA, qW, xsc, wsc, K, M);

  dim3 grid((M / 256) * (N / 256));
  gemm_fp8<<<grid, 512, 0, stream>>>(qA, qW, xsc, wsc, bias, out, M, N, K);
}